// Round 1
// baseline (436.680 us; speedup 1.0000x reference)
//
#include <hip/hip_runtime.h>
#include <stdint.h>

// Problem constants
#define S_DIM 512
#define B_DIM 64
#define T_DIM 768
#define A_DIM 512
#define H1_DIM 768
#define H2_DIM 640
#define N_DIM (H1_DIM + H2_DIM)   // 1408 combined hidden cols
#define M_DIM (S_DIM * B_DIM)     // 32768 rows
#define K_DIM T_DIM               // 768

typedef short s16x8 __attribute__((ext_vector_type(8)));
typedef float f32x4 __attribute__((ext_vector_type(4)));

__device__ __forceinline__ unsigned short f2bf(float f) {
    unsigned u = __float_as_uint(f);
    u += 0x7fffu + ((u >> 16) & 1u);   // round-to-nearest-even
    return (unsigned short)(u >> 16);
}

// --- convert text_seq fp32 -> bf16 (flat (M,K)) ---
__global__ __launch_bounds__(256) void convA_kernel(const float* __restrict__ ts,
                                                    unsigned short* __restrict__ Abf) {
    int i = blockIdx.x * 256 + threadIdx.x;   // over M*K/4 float4 groups
    float4 v = ((const float4*)ts)[i];
    ushort4 o;
    o.x = f2bf(v.x); o.y = f2bf(v.y); o.z = f2bf(v.z); o.w = f2bf(v.w);
    ((ushort4*)Abf)[i] = o;
}

// --- build combined B^T bf16: Bt[n][k], n<768 from W11[:T], else W12[:T] ---
__global__ __launch_bounds__(256) void convW_kernel(const float* __restrict__ W11,
                                                    const float* __restrict__ W12,
                                                    unsigned short* __restrict__ Bt) {
    int e = blockIdx.x * 256 + threadIdx.x;   // N_DIM*K_DIM
    int n = e / K_DIM, k = e % K_DIM;
    float v = (n < H1_DIM) ? W11[k * H1_DIM + n] : W12[k * H2_DIM + (n - H1_DIM)];
    Bt[e] = f2bf(v);
}

// --- per-batch bias c[b][n] = text@W11[T:] + b11 | anp@W12[T:] + b12 (fp32) ---
__global__ __launch_bounds__(256) void bias_kernel(const float* __restrict__ text,
                                                   const float* __restrict__ anp,
                                                   const float* __restrict__ W11,
                                                   const float* __restrict__ b11,
                                                   const float* __restrict__ W12,
                                                   const float* __restrict__ b12,
                                                   float* __restrict__ cbias) {
    int e = blockIdx.x * 256 + threadIdx.x;   // B_DIM*N_DIM
    int b = e / N_DIM, n = e % N_DIM;
    float acc;
    if (n < H1_DIM) {
        acc = b11[n];
        const float* w = W11 + (size_t)T_DIM * H1_DIM + n;
        const float* x = text + b * T_DIM;
        #pragma unroll 4
        for (int k = 0; k < T_DIM; ++k) acc = fmaf(x[k], w[(size_t)k * H1_DIM], acc);
    } else {
        int n2 = n - H1_DIM;
        acc = b12[n2];
        const float* w = W12 + (size_t)T_DIM * H2_DIM + n2;
        const float* x = anp + b * A_DIM;
        #pragma unroll 4
        for (int k = 0; k < A_DIM; ++k) acc = fmaf(x[k], w[(size_t)k * H2_DIM], acc);
    }
    cbias[e] = acc;
}

// --- main: bf16 MFMA GEMM with fused tanh-dot epilogue -> scores (2, M) ---
#define BM 128
#define BN 128
#define BK 64

__global__ __launch_bounds__(256, 2) void gemm_score_kernel(
        const unsigned short* __restrict__ A,    // (M,K) bf16
        const unsigned short* __restrict__ Bt,   // (N,K) bf16
        const float* __restrict__ cbias,         // (B,N)
        const float* __restrict__ W21,           // (768)
        const float* __restrict__ W22,           // (640)
        float* __restrict__ score) {             // (2,M) pre-zeroed
    __shared__ __align__(16) unsigned short As[BM * BK];   // 16 KB
    __shared__ __align__(16) unsigned short Bs[BN * BK];   // 16 KB
    const int tid  = threadIdx.x;
    const int m0   = blockIdx.x * BM;
    const int n0   = blockIdx.y * BN;
    const int lane = tid & 63;
    const int wave = tid >> 6;
    const int wm   = wave & 1;       // 2x2 waves over 128x128
    const int wn   = wave >> 1;
    const int quad = lane >> 4;
    const int col  = lane & 15;

    f32x4 acc[4][4] = {};            // 4x4 subtiles of 16x16 per wave
    const int sr = tid >> 3;         // staging row 0..31
    const int sk = (tid & 7) * 8;    // staging k offset (elements)

    for (int k0 = 0; k0 < K_DIM; k0 += BK) {
        #pragma unroll
        for (int p = 0; p < 4; ++p) {
            int r = p * 32 + sr;
            *(uint4*)&As[r * BK + sk] = *(const uint4*)&A[(m0 + r) * K_DIM + k0 + sk];
            *(uint4*)&Bs[r * BK + sk] = *(const uint4*)&Bt[(n0 + r) * K_DIM + k0 + sk];
        }
        __syncthreads();
        #pragma unroll
        for (int kk = 0; kk < BK; kk += 32) {
            s16x8 af[4], bf[4];
            #pragma unroll
            for (int i = 0; i < 4; ++i)
                af[i] = *(const s16x8*)&As[(wm * 64 + i * 16 + col) * BK + kk + quad * 8];
            #pragma unroll
            for (int j = 0; j < 4; ++j)
                bf[j] = *(const s16x8*)&Bs[(wn * 64 + j * 16 + col) * BK + kk + quad * 8];
            #pragma unroll
            for (int i = 0; i < 4; ++i)
                #pragma unroll
                for (int j = 0; j < 4; ++j)
                    acc[i][j] = __builtin_amdgcn_mfma_f32_16x16x32_bf16(af[i], bf[j], acc[i][j], 0, 0, 0);
        }
        __syncthreads();
    }

    // Epilogue: score[half][row] += sum_n tanh(acc + c[b][n]) * w2[n]
    const int half = (n0 >= H1_DIM) ? 1 : 0;     // 768 = 6*128, tiles never straddle
    const float* w2p = half ? (W22 - H1_DIM) : W21;
    int   ncol[4];
    float w2v[4];
    #pragma unroll
    for (int j = 0; j < 4; ++j) {
        ncol[j] = n0 + wn * 64 + j * 16 + col;
        w2v[j]  = w2p[ncol[j]];
    }
    float* sc = score + half * M_DIM;
    #pragma unroll
    for (int i = 0; i < 4; ++i) {
        #pragma unroll
        for (int r = 0; r < 4; ++r) {
            int row_local = wm * 64 + i * 16 + quad * 4 + r;   // C/D: row=quad*4+reg
            int b = row_local & (B_DIM - 1);                   // m0 % 64 == 0
            float v = 0.f;
            #pragma unroll
            for (int j = 0; j < 4; ++j) {
                float pre = acc[i][j][r] + cbias[b * N_DIM + ncol[j]];
                float ex  = __expf(2.f * pre);                 // tanh(x)=1-2/(e^{2x}+1)
                float th  = 1.f - 2.f * __builtin_amdgcn_rcpf(ex + 1.f);
                v = fmaf(th, w2v[j], v);
            }
            v += __shfl_xor(v, 1);    // reduce over the 16 cols (same quad = same row)
            v += __shfl_xor(v, 2);
            v += __shfl_xor(v, 4);
            v += __shfl_xor(v, 8);
            if (col == 0) atomicAdd(&sc[m0 + row_local], v);
        }
    }
}

// --- softmax over S per (b, half); wsum = w1 + w2 ---
__global__ __launch_bounds__(256) void softmax_kernel(const float* __restrict__ score,
                                                      float* __restrict__ wsum) {
    const int b = blockIdx.x, tid = threadIdx.x;
    __shared__ float red[256];
    for (int h = 0; h < 2; ++h) {
        const float* sc = score + h * M_DIM;
        float v0 = sc[tid * B_DIM + b];
        float v1 = sc[(tid + 256) * B_DIM + b];
        red[tid] = fmaxf(v0, v1);
        __syncthreads();
        for (int off = 128; off > 0; off >>= 1) {
            if (tid < off) red[tid] = fmaxf(red[tid], red[tid + off]);
            __syncthreads();
        }
        float m = red[0];
        __syncthreads();
        float e0 = expf(v0 - m), e1 = expf(v1 - m);
        red[tid] = e0 + e1;
        __syncthreads();
        for (int off = 128; off > 0; off >>= 1) {
            if (tid < off) red[tid] += red[tid + off];
            __syncthreads();
        }
        float z = 1.f / red[0];
        __syncthreads();
        if (h == 0) {
            wsum[tid * B_DIM + b]         = e0 * z;
            wsum[(tid + 256) * B_DIM + b] = e1 * z;
        } else {
            wsum[tid * B_DIM + b]         += e0 * z;
            wsum[(tid + 256) * B_DIM + b] += e1 * z;
        }
    }
}

// --- out[b,t] = (0.5/S) * sum_s wsum[s,b] * ts[s,b,t], s-split over grid.y ---
__global__ __launch_bounds__(256) void wmean_kernel(const float* __restrict__ ts,
                                                    const float* __restrict__ wsum,
                                                    float* __restrict__ out) {
    int e = blockIdx.x * 256 + threadIdx.x;   // over B*T
    int s0 = blockIdx.y * 64;
    int b = e / T_DIM, t = e % T_DIM;
    float acc = 0.f;
    #pragma unroll 4
    for (int s = s0; s < s0 + 64; ++s)
        acc = fmaf(wsum[s * B_DIM + b], ts[(s * B_DIM + b) * T_DIM + t], acc);
    atomicAdd(&out[e], acc * (0.5f / (float)S_DIM));
}

extern "C" void kernel_launch(void* const* d_in, const int* in_sizes, int n_in,
                              void* d_out, int out_size, void* d_ws, size_t ws_size,
                              hipStream_t stream) {
    const float* text = (const float*)d_in[0];
    const float* anp  = (const float*)d_in[1];
    const float* ts   = (const float*)d_in[2];
    const float* W11  = (const float*)d_in[3];
    const float* b11  = (const float*)d_in[4];
    const float* W21  = (const float*)d_in[5];
    // d_in[6] = b21: unused, softmax is shift-invariant
    const float* W12  = (const float*)d_in[7];
    const float* b12  = (const float*)d_in[8];
    const float* W22  = (const float*)d_in[9];
    // d_in[10] = b22: unused
    float* out = (float*)d_out;

    // workspace layout (bytes): total ~53.25 MB
    char* ws = (char*)d_ws;
    unsigned short* Abf = (unsigned short*)ws;                                   // 50331648
    unsigned short* Bt  = (unsigned short*)(ws + 50331648);                      //  2162688
    float* cbias = (float*)(ws + 50331648 + 2162688);                            //   360448
    float* score = (float*)(ws + 50331648 + 2162688 + 360448);                   //   262144
    float* wsum  = (float*)(ws + 50331648 + 2162688 + 360448 + 262144);          //   131072

    hipMemsetAsync(score, 0, 2 * M_DIM * sizeof(float), stream);
    hipMemsetAsync(out, 0, B_DIM * T_DIM * sizeof(float), stream);

    convA_kernel<<<M_DIM * K_DIM / 1024, 256, 0, stream>>>(ts, Abf);
    convW_kernel<<<N_DIM * K_DIM / 256, 256, 0, stream>>>(W11, W12, Bt);
    bias_kernel<<<B_DIM * N_DIM / 256, 256, 0, stream>>>(text, anp, W11, b11, W12, b12, cbias);
    gemm_score_kernel<<<dim3(M_DIM / BM, N_DIM / BN), 256, 0, stream>>>(Abf, Bt, cbias, W21, W22, score);
    softmax_kernel<<<B_DIM, 256, 0, stream>>>(score, wsum);
    wmean_kernel<<<dim3(B_DIM * T_DIM / 256, 8), 256, 0, stream>>>(ts, wsum, out);
}

// Round 2
// 379.322 us; speedup vs baseline: 1.1512x; 1.1512x over previous
//
#include <hip/hip_runtime.h>
#include <stdint.h>

// Problem constants
#define S_DIM 512
#define B_DIM 64
#define T_DIM 768
#define A_DIM 512
#define H1_DIM 768
#define H2_DIM 640
#define N_DIM (H1_DIM + H2_DIM)   // 1408 combined hidden cols
#define M_DIM (S_DIM * B_DIM)     // 32768 rows
#define K_DIM T_DIM               // 768

typedef short s16x8 __attribute__((ext_vector_type(8)));
typedef float f32x4 __attribute__((ext_vector_type(4)));

__device__ __forceinline__ unsigned short f2bf(float f) {
    unsigned u = __float_as_uint(f);
    u += 0x7fffu + ((u >> 16) & 1u);   // round-to-nearest-even
    return (unsigned short)(u >> 16);
}

// --- convert text_seq fp32 -> bf16 (flat (M,K)) ---
__global__ __launch_bounds__(256) void convA_kernel(const float* __restrict__ ts,
                                                    unsigned short* __restrict__ Abf) {
    int i = blockIdx.x * 256 + threadIdx.x;   // over M*K/4 float4 groups
    float4 v = ((const float4*)ts)[i];
    ushort4 o;
    o.x = f2bf(v.x); o.y = f2bf(v.y); o.z = f2bf(v.z); o.w = f2bf(v.w);
    ((ushort4*)Abf)[i] = o;
}

// --- build combined B^T bf16: Bt[n][k], n<768 from W11[:T], else W12[:T] ---
__global__ __launch_bounds__(256) void convW_kernel(const float* __restrict__ W11,
                                                    const float* __restrict__ W12,
                                                    unsigned short* __restrict__ Bt) {
    int e = blockIdx.x * 256 + threadIdx.x;   // N_DIM*K_DIM
    int n = e / K_DIM, k = e % K_DIM;
    float v = (n < H1_DIM) ? W11[k * H1_DIM + n] : W12[k * H2_DIM + (n - H1_DIM)];
    Bt[e] = f2bf(v);
}

// --- per-batch bias c[b][n] = text@W11[T:] + b11 | anp@W12[T:] + b12 (fp32) ---
__global__ __launch_bounds__(256) void bias_kernel(const float* __restrict__ text,
                                                   const float* __restrict__ anp,
                                                   const float* __restrict__ W11,
                                                   const float* __restrict__ b11,
                                                   const float* __restrict__ W12,
                                                   const float* __restrict__ b12,
                                                   float* __restrict__ cbias) {
    int e = blockIdx.x * 256 + threadIdx.x;   // B_DIM*N_DIM
    int b = e / N_DIM, n = e % N_DIM;
    float a0 = 0.f, a1 = 0.f, a2 = 0.f, a3 = 0.f, base;
    if (n < H1_DIM) {
        base = b11[n];
        const float* w = W11 + (size_t)T_DIM * H1_DIM + n;
        const float* x = text + b * T_DIM;
        for (int k = 0; k < T_DIM; k += 4) {
            a0 = fmaf(x[k],     w[(size_t)k * H1_DIM],       a0);
            a1 = fmaf(x[k + 1], w[(size_t)(k + 1) * H1_DIM], a1);
            a2 = fmaf(x[k + 2], w[(size_t)(k + 2) * H1_DIM], a2);
            a3 = fmaf(x[k + 3], w[(size_t)(k + 3) * H1_DIM], a3);
        }
    } else {
        int n2 = n - H1_DIM;
        base = b12[n2];
        const float* w = W12 + (size_t)T_DIM * H2_DIM + n2;
        const float* x = anp + b * A_DIM;
        for (int k = 0; k < A_DIM; k += 4) {
            a0 = fmaf(x[k],     w[(size_t)k * H2_DIM],       a0);
            a1 = fmaf(x[k + 1], w[(size_t)(k + 1) * H2_DIM], a1);
            a2 = fmaf(x[k + 2], w[(size_t)(k + 2) * H2_DIM], a2);
            a3 = fmaf(x[k + 3], w[(size_t)(k + 3) * H2_DIM], a3);
        }
    }
    cbias[e] = base + ((a0 + a1) + (a2 + a3));
}

// --- main: bf16 MFMA GEMM with fused tanh-dot epilogue -> scores [2][B][S] ---
#define BM 128
#define BN 128
#define BK 64

__global__ __launch_bounds__(256, 2) void gemm_score_kernel(
        const unsigned short* __restrict__ A,    // (M,K) bf16
        const unsigned short* __restrict__ Bt,   // (N,K) bf16
        const float* __restrict__ cbias,         // (B,N)
        const float* __restrict__ W21,           // (768)
        const float* __restrict__ W22,           // (640)
        float* __restrict__ score) {             // [2][B][S] pre-zeroed
    __shared__ __align__(16) unsigned short As[BM * BK];   // 16 KB
    __shared__ __align__(16) unsigned short Bs[BN * BK];   // 16 KB
    const int tid  = threadIdx.x;
    const int m0   = blockIdx.x * BM;
    const int n0   = blockIdx.y * BN;
    const int lane = tid & 63;
    const int wave = tid >> 6;
    const int wm   = wave & 1;       // 2x2 waves over 128x128
    const int wn   = wave >> 1;
    const int quad = lane >> 4;
    const int col  = lane & 15;

    f32x4 acc[4][4] = {};            // 4x4 subtiles of 16x16 per wave

    // global_load_lds staging: wave covers 8 rows x 64 k (1 KB contiguous LDS)
    const int wrow = lane >> 3;          // 0..7 row within wave's 8-row group
    const int kof  = (lane & 7) * 8;     // bf16 element offset within row

    for (int k0 = 0; k0 < K_DIM; k0 += BK) {
        #pragma unroll
        for (int p = 0; p < 4; ++p) {
            const int r0 = p * 32 + wave * 8;    // wave-uniform row group
            __builtin_amdgcn_global_load_lds(
                (__attribute__((address_space(1))) void*)&A[(size_t)(m0 + r0 + wrow) * K_DIM + k0 + kof],
                (__attribute__((address_space(3))) void*)&As[r0 * BK],
                16, 0, 0);
            __builtin_amdgcn_global_load_lds(
                (__attribute__((address_space(1))) void*)&Bt[(size_t)(n0 + r0 + wrow) * K_DIM + k0 + kof],
                (__attribute__((address_space(3))) void*)&Bs[r0 * BK],
                16, 0, 0);
        }
        __syncthreads();
        #pragma unroll
        for (int kk = 0; kk < BK; kk += 32) {
            s16x8 af[4], bf[4];
            #pragma unroll
            for (int i = 0; i < 4; ++i)
                af[i] = *(const s16x8*)&As[(wm * 64 + i * 16 + col) * BK + kk + quad * 8];
            #pragma unroll
            for (int j = 0; j < 4; ++j)
                bf[j] = *(const s16x8*)&Bs[(wn * 64 + j * 16 + col) * BK + kk + quad * 8];
            #pragma unroll
            for (int i = 0; i < 4; ++i)
                #pragma unroll
                for (int j = 0; j < 4; ++j)
                    acc[i][j] = __builtin_amdgcn_mfma_f32_16x16x32_bf16(af[i], bf[j], acc[i][j], 0, 0, 0);
        }
        __syncthreads();
    }

    // Epilogue: score[half][b][s] += sum_n tanh(acc + c[b][n]) * w2[n]
    const int half = (n0 >= H1_DIM) ? 1 : 0;     // 768 = 6*128, tiles never straddle
    const float* w2p = half ? (W22 - H1_DIM) : W21;
    int   ncol[4];
    float w2v[4];
    #pragma unroll
    for (int j = 0; j < 4; ++j) {
        ncol[j] = n0 + wn * 64 + j * 16 + col;
        w2v[j]  = w2p[ncol[j]];
    }
    float* sc = score + half * M_DIM;
    #pragma unroll
    for (int i = 0; i < 4; ++i) {
        #pragma unroll
        for (int r = 0; r < 4; ++r) {
            int row_local = wm * 64 + i * 16 + quad * 4 + r;   // C/D: row=quad*4+reg
            int b = row_local & (B_DIM - 1);                   // m0 % 128 == 0
            int s = (m0 + row_local) >> 6;
            float v = 0.f;
            #pragma unroll
            for (int j = 0; j < 4; ++j) {
                float pre = acc[i][j][r] + cbias[b * N_DIM + ncol[j]];
                float ex  = __expf(2.f * pre);                 // tanh(x)=1-2/(e^{2x}+1)
                float th  = 1.f - 2.f * __builtin_amdgcn_rcpf(ex + 1.f);
                v = fmaf(th, w2v[j], v);
            }
            v += __shfl_xor(v, 1);    // reduce over the 16 cols (same quad = same row)
            v += __shfl_xor(v, 2);
            v += __shfl_xor(v, 4);
            v += __shfl_xor(v, 8);
            if (col == 0) atomicAdd(&sc[b * S_DIM + s], v);
        }
    }
}

// --- softmax over S per (b, half); wsum[b][s] = w1 + w2; one block per b ---
__global__ __launch_bounds__(512) void softmax_kernel(const float* __restrict__ score,
                                                      float* __restrict__ wsum) {
    const int b = blockIdx.x, s = threadIdx.x;   // 512 threads = 512 s
    __shared__ float redm[16], reds[16];
    float v0 = score[b * S_DIM + s];
    float v1 = score[M_DIM + b * S_DIM + s];
    float m0 = v0, m1 = v1;
    #pragma unroll
    for (int off = 32; off > 0; off >>= 1) {
        m0 = fmaxf(m0, __shfl_xor(m0, off));
        m1 = fmaxf(m1, __shfl_xor(m1, off));
    }
    const int w = s >> 6;
    if ((s & 63) == 0) { redm[w] = m0; redm[8 + w] = m1; }
    __syncthreads();
    m0 = redm[0]; m1 = redm[8];
    #pragma unroll
    for (int i = 1; i < 8; ++i) { m0 = fmaxf(m0, redm[i]); m1 = fmaxf(m1, redm[8 + i]); }
    float e0 = expf(v0 - m0), e1 = expf(v1 - m1);
    float s0 = e0, s1 = e1;
    #pragma unroll
    for (int off = 32; off > 0; off >>= 1) {
        s0 += __shfl_xor(s0, off);
        s1 += __shfl_xor(s1, off);
    }
    if ((s & 63) == 0) { reds[w] = s0; reds[8 + w] = s1; }
    __syncthreads();
    s0 = reds[0]; s1 = reds[8];
    #pragma unroll
    for (int i = 1; i < 8; ++i) { s0 += reds[i]; s1 += reds[8 + i]; }
    wsum[b * S_DIM + s] = e0 / s0 + e1 / s1;
}

// --- out[b,t] = (0.5/S) * sum_s wsum[b][s] * ts[s,b,t], s-split over grid.y ---
__global__ __launch_bounds__(256) void wmean_kernel(const float* __restrict__ ts,
                                                    const float* __restrict__ wsum,
                                                    float* __restrict__ out) {
    int e = blockIdx.x * 256 + threadIdx.x;   // over B*T
    int s0 = blockIdx.y * 32;
    int b = e / T_DIM, t = e % T_DIM;
    float a0 = 0.f, a1 = 0.f;
    #pragma unroll 4
    for (int s = s0; s < s0 + 32; s += 2) {
        a0 = fmaf(wsum[b * S_DIM + s],     ts[(size_t)(s * B_DIM + b) * T_DIM + t],       a0);
        a1 = fmaf(wsum[b * S_DIM + s + 1], ts[(size_t)((s + 1) * B_DIM + b) * T_DIM + t], a1);
    }
    atomicAdd(&out[e], (a0 + a1) * (0.5f / (float)S_DIM));
}

extern "C" void kernel_launch(void* const* d_in, const int* in_sizes, int n_in,
                              void* d_out, int out_size, void* d_ws, size_t ws_size,
                              hipStream_t stream) {
    const float* text = (const float*)d_in[0];
    const float* anp  = (const float*)d_in[1];
    const float* ts   = (const float*)d_in[2];
    const float* W11  = (const float*)d_in[3];
    const float* b11  = (const float*)d_in[4];
    const float* W21  = (const float*)d_in[5];
    // d_in[6] = b21: unused, softmax is shift-invariant
    const float* W12  = (const float*)d_in[7];
    const float* b12  = (const float*)d_in[8];
    const float* W22  = (const float*)d_in[9];
    // d_in[10] = b22: unused
    float* out = (float*)d_out;

    // workspace layout (bytes): total ~53.25 MB
    char* ws = (char*)d_ws;
    unsigned short* Abf = (unsigned short*)ws;                                   // 50331648
    unsigned short* Bt  = (unsigned short*)(ws + 50331648);                      //  2162688
    float* cbias = (float*)(ws + 50331648 + 2162688);                            //   360448
    float* score = (float*)(ws + 50331648 + 2162688 + 360448);                   //   262144
    float* wsum  = (float*)(ws + 50331648 + 2162688 + 360448 + 262144);          //   131072

    hipMemsetAsync(score, 0, 2 * M_DIM * sizeof(float), stream);
    hipMemsetAsync(out, 0, B_DIM * T_DIM * sizeof(float), stream);

    convA_kernel<<<M_DIM * K_DIM / 1024, 256, 0, stream>>>(ts, Abf);
    convW_kernel<<<N_DIM * K_DIM / 256, 256, 0, stream>>>(W11, W12, Bt);
    bias_kernel<<<B_DIM * N_DIM / 256, 256, 0, stream>>>(text, anp, W11, b11, W12, b12, cbias);
    gemm_score_kernel<<<dim3(M_DIM / BM, N_DIM / BN), 256, 0, stream>>>(Abf, Bt, cbias, W21, W22, score);
    softmax_kernel<<<B_DIM, 512, 0, stream>>>(score, wsum);
    wmean_kernel<<<dim3(B_DIM * T_DIM / 256, 16), 256, 0, stream>>>(ts, wsum, out);
}